// Round 7
// baseline (294.631 us; speedup 1.0000x reference)
//
#include <hip/hip_runtime.h>
#include <stdint.h>

#define B_   8
#define N_   2048
#define C_   128
#define EPS_ 0.1f

typedef __attribute__((ext_vector_type(8))) short short8;
typedef __attribute__((ext_vector_type(4))) float f32x4;

__device__ __forceinline__ unsigned short f2bf(float f) {
    union { float f; uint32_t u; } v; v.f = f;
    uint32_t u = v.u + 0x7FFF + ((v.u >> 16) & 1);   // RNE (inputs are finite)
    return (unsigned short)(u >> 16);
}

// ------------- kernel P: pack adj (int32 0/1) -> bitmask, 32x smaller -------------
__global__ __launch_bounds__(256) void k_pack(const int* __restrict__ adj,
                                              unsigned int* __restrict__ pk) {
    __shared__ unsigned char bytes[256];
    const int g = blockIdx.x, t = threadIdx.x;
    const size_t base = ((size_t)g * 256 + t) * 8;
    int4 a = *(const int4*)(adj + base);
    int4 b = *(const int4*)(adj + base + 4);
    unsigned int m =
        (a.x ? 1u   : 0u) | (a.y ? 2u   : 0u) | (a.z ? 4u  : 0u) | (a.w ? 8u   : 0u) |
        (b.x ? 16u  : 0u) | (b.y ? 32u  : 0u) | (b.z ? 64u : 0u) | (b.w ? 128u : 0u);
    bytes[t] = (unsigned char)m;
    __syncthreads();
    if (t < 64) {
        unsigned int w = (unsigned int)bytes[4*t]
                       | ((unsigned int)bytes[4*t+1] << 8)
                       | ((unsigned int)bytes[4*t+2] << 16)
                       | ((unsigned int)bytes[4*t+3] << 24);
        pk[(size_t)g * 64 + t] = w;
    }
}

// ---------------- kernel 0: Wt[o][k] = bf16(W[k][o]) ----------------
__global__ __launch_bounds__(128) void k_wt(const float* __restrict__ W,
                                            unsigned short* __restrict__ Wt) {
    const int o = blockIdx.x, k = threadIdx.x;
    Wt[o * C_ + k] = f2bf(W[k * C_ + o]);
}

// ---- kernel 1: ht[b][o][j]=bf16(h), al/ar = h . w_att (MFMA x@W) ----
__global__ __launch_bounds__(256) void k_h(
    const float* __restrict__ x, const unsigned short* __restrict__ Wt,
    const float* __restrict__ wl, const float* __restrict__ wr,
    unsigned short* __restrict__ ht, float* __restrict__ al, float* __restrict__ ar)
{
    const int b    = blockIdx.x >> 5;
    const int i0   = (blockIdx.x & 31) * 64;
    const int t    = threadIdx.x;
    const int lane = t & 63;
    const int wid  = t >> 6;

    __shared__ __align__(16) unsigned short xs[64 * 128];
    __shared__ __align__(16) unsigned short ws[128 * 128];

    #pragma unroll
    for (int p = 0; p < 4; ++p) {
        const int s = p * 256 + t, row = s >> 4, u = s & 15;
        const float* gp = x + ((size_t)(b * N_ + i0 + row) * C_ + u * 8);
        float4 f0 = *(const float4*)gp;
        float4 f1 = *(const float4*)(gp + 4);
        short8 tv;
        tv[0] = (short)f2bf(f0.x); tv[1] = (short)f2bf(f0.y);
        tv[2] = (short)f2bf(f0.z); tv[3] = (short)f2bf(f0.w);
        tv[4] = (short)f2bf(f1.x); tv[5] = (short)f2bf(f1.y);
        tv[6] = (short)f2bf(f1.z); tv[7] = (short)f2bf(f1.w);
        *(short8*)&xs[row * 128 + (u ^ (row & 15)) * 8] = tv;
    }
    #pragma unroll
    for (int p = 0; p < 8; ++p) {
        const int s = p * 256 + t, o = s >> 4, u = s & 15;
        int4 v = *(const int4*)(Wt + o * C_ + u * 8);
        *(int4*)&ws[o * 128 + (u ^ (o & 15)) * 8] = v;
    }
    __syncthreads();

    const int m0 = wid * 16, lr = lane & 15, q = lane >> 4;
    f32x4 acc[8];
    #pragma unroll
    for (int i = 0; i < 8; ++i) acc[i] = (f32x4){0.f, 0.f, 0.f, 0.f};

    #pragma unroll
    for (int s = 0; s < 4; ++s) {
        const int m = m0 + lr;
        short8 af = *(const short8*)&xs[m * 128 + ((s * 4 + q) ^ (m & 15)) * 8];
        #pragma unroll
        for (int tt = 0; tt < 8; ++tt) {
            const int o = tt * 16 + lr;
            short8 bf = *(const short8*)&ws[o * 128 + ((s * 4 + q) ^ (o & 15)) * 8];
            acc[tt] = __builtin_amdgcn_mfma_f32_16x16x32_bf16(af, bf, acc[tt], 0, 0, 0);
        }
    }

    float pl[4] = {0.f, 0.f, 0.f, 0.f}, pr[4] = {0.f, 0.f, 0.f, 0.f};
    const int j0 = i0 + m0 + q * 4;
    #pragma unroll
    for (int tt = 0; tt < 8; ++tt) {
        const int o = tt * 16 + lr;
        const float wlv = wl[o], wrv = wr[o];
        unsigned int lo = (unsigned int)f2bf(acc[tt][0]) | ((unsigned int)f2bf(acc[tt][1]) << 16);
        unsigned int hi = (unsigned int)f2bf(acc[tt][2]) | ((unsigned int)f2bf(acc[tt][3]) << 16);
        uint2 u2; u2.x = lo; u2.y = hi;
        *(uint2*)&ht[((size_t)(b * C_ + o)) * N_ + j0] = u2;
        #pragma unroll
        for (int r = 0; r < 4; ++r) {
            pl[r] = fmaf(acc[tt][r], wlv, pl[r]);
            pr[r] = fmaf(acc[tt][r], wrv, pr[r]);
        }
    }
    #pragma unroll
    for (int msk = 1; msk < 16; msk <<= 1) {
        #pragma unroll
        for (int r = 0; r < 4; ++r) {
            pl[r] += __shfl_xor(pl[r], msk, 64);
            pr[r] += __shfl_xor(pr[r], msk, 64);
        }
    }
    if (lr == 0) {
        #pragma unroll
        for (int r = 0; r < 4; ++r) {
            al[b * N_ + j0 + r] = pl[r];
            ar[b * N_ + j0 + r] = pr[r];
        }
    }
}

// ---- kernel 2: out = mask(tanh(ar_i*al_j)) @ h + eps*x0 ----
// Barrier-free, LDS-free; adj comes from the packed bitmask (L2/L3-resident),
// so the only HBM traffic is x0/out. 512 blocks x 256 thr, i-tile 32.
struct PrefO {                      // one 32-j k-step of per-lane operands
    unsigned int w;                 // packed adj bits for (row, 32-j block)
    float4 l0, l1;                  // al [jb + q*8 .. +7]
    int4   h0, h1, h2, h3;          // ht rows n0+{0,16,32,48}+r, 8 bf16 each
};

__global__ __launch_bounds__(256, 2) void k_out(
    const unsigned int* __restrict__ pk, const unsigned short* __restrict__ ht,
    const float* __restrict__ al, const float* __restrict__ ar,
    const float* __restrict__ x0, float* __restrict__ out)
{
    const int b    = blockIdx.x >> 6;
    const int i0   = (blockIdx.x & 63) * 32;
    const int t    = threadIdx.x;
    const int lane = t & 63;
    const int wid  = t >> 6;
    const int m0   = (wid & 1) * 16, n0 = (wid >> 1) * 64;
    const int r    = lane & 15, q = lane >> 4;

    const int row   = i0 + m0 + r;                      // A-frag m-row
    const float arv = ar[b * N_ + row];

    const unsigned int*   pkp  = pk + ((size_t)(b * N_ + row)) * (N_ / 32);
    const float*          alp  = al + b * N_ + q * 8;
    const unsigned short* hb   = ht + (size_t)b * C_ * N_ + q * 8;
    const unsigned short* hp0  = hb + (size_t)(n0 +  0 + r) * N_;
    const unsigned short* hp1  = hb + (size_t)(n0 + 16 + r) * N_;
    const unsigned short* hp2  = hb + (size_t)(n0 + 32 + r) * N_;
    const unsigned short* hp3  = hb + (size_t)(n0 + 48 + r) * N_;

    auto ld = [&](int s) -> PrefO {
        PrefO P; const int jb = s * 32;
        P.w  = pkp[s];
        P.l0 = *(const float4*)(alp + jb);
        P.l1 = *(const float4*)(alp + jb + 4);
        P.h0 = *(const int4*)(hp0 + jb);
        P.h1 = *(const int4*)(hp1 + jb);
        P.h2 = *(const int4*)(hp2 + jb);
        P.h3 = *(const int4*)(hp3 + jb);
        return P;
    };

    f32x4 acc[4];
    #pragma unroll
    for (int i = 0; i < 4; ++i) acc[i] = (f32x4){0.f, 0.f, 0.f, 0.f};

    auto step = [&](const PrefO& P) {
        const float* lv = (const float*)&P.l0;  // l0,l1 contiguous; const idx only
        const unsigned int wbits = P.w >> (q * 8);
        short8 af;
        #pragma unroll
        for (int e = 0; e < 8; ++e) {
            float z  = arv * lv[e];
            float ex = __expf(2.f * z);
            float th = 1.f - 2.f * __builtin_amdgcn_rcpf(ex + 1.f);
            af[e] = ((wbits >> e) & 1u) ? (short)f2bf(th) : (short)0;
        }
        acc[0] = __builtin_amdgcn_mfma_f32_16x16x32_bf16(af, *(const short8*)&P.h0, acc[0], 0, 0, 0);
        acc[1] = __builtin_amdgcn_mfma_f32_16x16x32_bf16(af, *(const short8*)&P.h1, acc[1], 0, 0, 0);
        acc[2] = __builtin_amdgcn_mfma_f32_16x16x32_bf16(af, *(const short8*)&P.h2, acc[2], 0, 0, 0);
        acc[3] = __builtin_amdgcn_mfma_f32_16x16x32_bf16(af, *(const short8*)&P.h3, acc[3], 0, 0, 0);
    };

    PrefO A  = ld(0);
    PrefO Bp = ld(1);
    for (int it = 0; it < 32; ++it) {
        step(A);
        if (it < 31) A = ld(2 * it + 2);
        step(Bp);
        if (it < 31) Bp = ld(2 * it + 3);
    }

    // ---- epilogue: out = acc + eps*x0 (C-layout: col=lane&15, row=q*4+reg) ----
    #pragma unroll
    for (int tt = 0; tt < 4; ++tt) {
        const int o = n0 + tt * 16 + r;
        #pragma unroll
        for (int rr = 0; rr < 4; ++rr) {
            const int orow = i0 + m0 + q * 4 + rr;
            const size_t idx = ((size_t)(b * N_) + orow) * C_ + o;
            out[idx] = acc[tt][rr] + EPS_ * x0[idx];
        }
    }
}

extern "C" void kernel_launch(void* const* d_in, const int* in_sizes, int n_in,
                              void* d_out, int out_size, void* d_ws, size_t ws_size,
                              hipStream_t stream) {
    const float* x   = (const float*)d_in[0];
    const float* x0  = (const float*)d_in[1];
    const int*   adj = (const int*)d_in[2];
    const float* W   = (const float*)d_in[3];
    const float* wl  = (const float*)d_in[4];
    const float* wr  = (const float*)d_in[5];
    float* out = (float*)d_out;

    unsigned short* ht = (unsigned short*)d_ws;                      // 4 MB
    float* al = (float*)((char*)d_ws + (size_t)B_ * C_ * N_ * 2);
    float* ar = al + B_ * N_;
    unsigned short* Wt = (unsigned short*)(ar + B_ * N_);            // 32 KB
    unsigned int*   pkb = (unsigned int*)(Wt + C_ * C_);             // 4.2 MB

    k_pack<<<(B_ * N_ * N_) / 2048, 256, 0, stream>>>(adj, pkb);
    k_wt  <<<C_,             C_,  0, stream>>>(W, Wt);
    k_h   <<<B_ * (N_ / 64), 256, 0, stream>>>(x, Wt, wl, wr, ht, al, ar);
    k_out <<<B_ * (N_ / 32), 256, 0, stream>>>(pkb, ht, al, ar, x0, out);
}

// Round 8
// 243.670 us; speedup vs baseline: 1.2091x; 1.2091x over previous
//
#include <hip/hip_runtime.h>
#include <stdint.h>

#define B_   8
#define N_   2048
#define C_   128
#define EPS_ 0.1f

typedef __attribute__((ext_vector_type(8))) short short8;
typedef __attribute__((ext_vector_type(4))) float f32x4;

__device__ __forceinline__ unsigned short f2bf(float f) {
    union { float f; uint32_t u; } v; v.f = f;
    uint32_t u = v.u + 0x7FFF + ((v.u >> 16) & 1);   // RNE (inputs are finite)
    return (unsigned short)(u >> 16);
}

// ------------- kernel P: pack adj (int32 0/1) -> bitmask, 32x smaller -------------
__global__ __launch_bounds__(256) void k_pack(const int* __restrict__ adj,
                                              unsigned int* __restrict__ pk) {
    __shared__ unsigned char bytes[256];
    const int g = blockIdx.x, t = threadIdx.x;
    const size_t base = ((size_t)g * 256 + t) * 8;
    int4 a = *(const int4*)(adj + base);
    int4 b = *(const int4*)(adj + base + 4);
    unsigned int m =
        (a.x ? 1u   : 0u) | (a.y ? 2u   : 0u) | (a.z ? 4u  : 0u) | (a.w ? 8u   : 0u) |
        (b.x ? 16u  : 0u) | (b.y ? 32u  : 0u) | (b.z ? 64u : 0u) | (b.w ? 128u : 0u);
    bytes[t] = (unsigned char)m;
    __syncthreads();
    if (t < 64) {
        unsigned int w = (unsigned int)bytes[4*t]
                       | ((unsigned int)bytes[4*t+1] << 8)
                       | ((unsigned int)bytes[4*t+2] << 16)
                       | ((unsigned int)bytes[4*t+3] << 24);
        pk[(size_t)g * 64 + t] = w;
    }
}

// ---------------- kernel 0: Wt[o][k] = bf16(W[k][o]) ----------------
__global__ __launch_bounds__(128) void k_wt(const float* __restrict__ W,
                                            unsigned short* __restrict__ Wt) {
    const int o = blockIdx.x, k = threadIdx.x;
    Wt[o * C_ + k] = f2bf(W[k * C_ + o]);
}

// ---- kernel 1: ht[b][o][j]=bf16(h), al/ar = h . w_att (MFMA x@W) ----
__global__ __launch_bounds__(256) void k_h(
    const float* __restrict__ x, const unsigned short* __restrict__ Wt,
    const float* __restrict__ wl, const float* __restrict__ wr,
    unsigned short* __restrict__ ht, float* __restrict__ al, float* __restrict__ ar)
{
    const int b    = blockIdx.x >> 5;
    const int i0   = (blockIdx.x & 31) * 64;
    const int t    = threadIdx.x;
    const int lane = t & 63;
    const int wid  = t >> 6;

    __shared__ __align__(16) unsigned short xs[64 * 128];
    __shared__ __align__(16) unsigned short ws[128 * 128];

    #pragma unroll
    for (int p = 0; p < 4; ++p) {
        const int s = p * 256 + t, row = s >> 4, u = s & 15;
        const float* gp = x + ((size_t)(b * N_ + i0 + row) * C_ + u * 8);
        float4 f0 = *(const float4*)gp;
        float4 f1 = *(const float4*)(gp + 4);
        short8 tv;
        tv[0] = (short)f2bf(f0.x); tv[1] = (short)f2bf(f0.y);
        tv[2] = (short)f2bf(f0.z); tv[3] = (short)f2bf(f0.w);
        tv[4] = (short)f2bf(f1.x); tv[5] = (short)f2bf(f1.y);
        tv[6] = (short)f2bf(f1.z); tv[7] = (short)f2bf(f1.w);
        *(short8*)&xs[row * 128 + (u ^ (row & 15)) * 8] = tv;
    }
    #pragma unroll
    for (int p = 0; p < 8; ++p) {
        const int s = p * 256 + t, o = s >> 4, u = s & 15;
        int4 v = *(const int4*)(Wt + o * C_ + u * 8);
        *(int4*)&ws[o * 128 + (u ^ (o & 15)) * 8] = v;
    }
    __syncthreads();

    const int m0 = wid * 16, lr = lane & 15, q = lane >> 4;
    f32x4 acc[8];
    #pragma unroll
    for (int i = 0; i < 8; ++i) acc[i] = (f32x4){0.f, 0.f, 0.f, 0.f};

    #pragma unroll
    for (int s = 0; s < 4; ++s) {
        const int m = m0 + lr;
        short8 af = *(const short8*)&xs[m * 128 + ((s * 4 + q) ^ (m & 15)) * 8];
        #pragma unroll
        for (int tt = 0; tt < 8; ++tt) {
            const int o = tt * 16 + lr;
            short8 bf = *(const short8*)&ws[o * 128 + ((s * 4 + q) ^ (o & 15)) * 8];
            acc[tt] = __builtin_amdgcn_mfma_f32_16x16x32_bf16(af, bf, acc[tt], 0, 0, 0);
        }
    }

    float pl[4] = {0.f, 0.f, 0.f, 0.f}, pr[4] = {0.f, 0.f, 0.f, 0.f};
    const int j0 = i0 + m0 + q * 4;
    #pragma unroll
    for (int tt = 0; tt < 8; ++tt) {
        const int o = tt * 16 + lr;
        const float wlv = wl[o], wrv = wr[o];
        unsigned int lo = (unsigned int)f2bf(acc[tt][0]) | ((unsigned int)f2bf(acc[tt][1]) << 16);
        unsigned int hi = (unsigned int)f2bf(acc[tt][2]) | ((unsigned int)f2bf(acc[tt][3]) << 16);
        uint2 u2; u2.x = lo; u2.y = hi;
        *(uint2*)&ht[((size_t)(b * C_ + o)) * N_ + j0] = u2;
        #pragma unroll
        for (int r = 0; r < 4; ++r) {
            pl[r] = fmaf(acc[tt][r], wlv, pl[r]);
            pr[r] = fmaf(acc[tt][r], wrv, pr[r]);
        }
    }
    #pragma unroll
    for (int msk = 1; msk < 16; msk <<= 1) {
        #pragma unroll
        for (int r = 0; r < 4; ++r) {
            pl[r] += __shfl_xor(pl[r], msk, 64);
            pr[r] += __shfl_xor(pr[r], msk, 64);
        }
    }
    if (lr == 0) {
        #pragma unroll
        for (int r = 0; r < 4; ++r) {
            al[b * N_ + j0 + r] = pl[r];
            ar[b * N_ + j0 + r] = pr[r];
        }
    }
}

// ---- kernel 2: out = mask(tanh(ar_i*al_j)) @ h + eps*x0  (MFMA, LDS-staged) ----
// 512 blocks x 256 thr, i-tile 32, full n=128; double-buffered LDS; operands
// from packed adj bitmask + L2-resident ht/al; prefetch issued right after
// each barrier so the barrier vmcnt-drain hits loads a full phase old.
struct Pref {                       // one 64-j K-chunk of per-thread operands
    unsigned int w;                 // pk word covering this thread's 8 j (+24 more)
    float4 l0, l1;                  // al [jb + jq*8 .. +7]
    int4   h0, h1, h2, h3;          // ht rows arow+{0,32,64,96}, 8 bf16 each
};

__global__ __launch_bounds__(256, 2) void k_out(
    const unsigned int* __restrict__ pk, const unsigned short* __restrict__ ht,
    const float* __restrict__ al, const float* __restrict__ ar,
    const float* __restrict__ x0, float* __restrict__ out)
{
    const int b    = blockIdx.x >> 6;
    const int i0   = (blockIdx.x & 63) * 32;
    const int t    = threadIdx.x;
    const int lane = t & 63;
    const int wid  = t >> 6;

    // K-chunk = 64 j, double-buffered. XOR-swizzle 16B units: u' = u ^ (row&7)
    __shared__ __align__(16) unsigned short a_s[2][32 * 64];    //  8 KB
    __shared__ __align__(16) unsigned short h_s[2][128 * 64];   // 32 KB

    const int arow = t >> 3;            // 0..31: i-row within tile & ht stage row
    const int jq   = t & 7;             // 8-j unit within chunk
    const float arv = ar[b * N_ + i0 + arow];

    const unsigned int*   pkp = pk + ((size_t)(b * N_ + i0 + arow)) * (N_ / 32);
    const float*          alp = al + b * N_ + jq * 8;
    const unsigned short* hb  = ht + (size_t)b * C_ * N_ + jq * 8;
    const unsigned short* hp0 = hb + (size_t)(arow)      * N_;
    const unsigned short* hp1 = hb + (size_t)(arow + 32) * N_;
    const unsigned short* hp2 = hb + (size_t)(arow + 64) * N_;
    const unsigned short* hp3 = hb + (size_t)(arow + 96) * N_;

    auto ldc = [&](int c) -> Pref {
        Pref P; const int jb = c * 64;
        P.w  = pkp[2 * c + (jq >> 2)];
        P.l0 = *(const float4*)(alp + jb);
        P.l1 = *(const float4*)(alp + jb + 4);
        P.h0 = *(const int4*)(hp0 + jb);
        P.h1 = *(const int4*)(hp1 + jb);
        P.h2 = *(const int4*)(hp2 + jb);
        P.h3 = *(const int4*)(hp3 + jb);
        return P;
    };

    auto stage = [&](int buf, const Pref& P) {
        const float* lv = (const float*)&P.l0;   // l0,l1 contiguous; const idx only
        const unsigned int wbits = P.w >> ((jq & 3) * 8);
        short8 pk8;
        #pragma unroll
        for (int e = 0; e < 8; ++e) {
            float z  = arv * lv[e];
            float ex = __expf(2.f * z);
            float th = 1.f - 2.f * __builtin_amdgcn_rcpf(ex + 1.f);
            pk8[e] = ((wbits >> e) & 1u) ? (short)f2bf(th) : (short)0;
        }
        const int su = (jq ^ (arow & 7)) * 8;
        *(short8*)&a_s[buf][arow * 64 + su] = pk8;
        *(int4*)&h_s[buf][(arow)      * 64 + su] = P.h0;
        *(int4*)&h_s[buf][(arow + 32) * 64 + su] = P.h1;
        *(int4*)&h_s[buf][(arow + 64) * 64 + su] = P.h2;
        *(int4*)&h_s[buf][(arow + 96) * 64 + su] = P.h3;
    };

    const int m0 = (wid & 1) * 16, n0 = (wid >> 1) * 64;
    const int lr = lane & 15, q = lane >> 4;
    f32x4 acc[4];
    #pragma unroll
    for (int i = 0; i < 4; ++i) acc[i] = (f32x4){0.f, 0.f, 0.f, 0.f};

    auto mma = [&](int buf) {
        #pragma unroll
        for (int s2 = 0; s2 < 2; ++s2) {
            const int m = m0 + lr;
            short8 afr = *(const short8*)&a_s[buf][m * 64 + ((s2 * 4 + q) ^ (m & 7)) * 8];
            #pragma unroll
            for (int tt = 0; tt < 4; ++tt) {
                const int o = n0 + tt * 16 + lr;
                short8 bfr = *(const short8*)&h_s[buf][o * 64 + ((s2 * 4 + q) ^ (o & 7)) * 8];
                acc[tt] = __builtin_amdgcn_mfma_f32_16x16x32_bf16(afr, bfr, acc[tt], 0, 0, 0);
            }
        }
    };

    // Preamble: buf0 <- chunk0; pA = chunk1, pB = chunk2.
    {
        Pref p = ldc(0);
        stage(0, p);
    }
    Pref pA = ldc(1);
    Pref pB = ldc(2);
    __syncthreads();

    // Invariant at iter top: buf0 = chunk 2cc, pA = 2cc+1, pB = 2cc+2.
    for (int cc = 0; cc < 16; ++cc) {
        stage(1, pA);                       // buf1 <- chunk 2cc+1
        mma(0);                             // chunk 2cc
        __syncthreads();
        if (cc < 15) pA = ldc(2 * cc + 3);  // issue right after barrier

        stage(0, pB);                       // buf0 <- chunk 2cc+2 (dead write at cc=15)
        mma(1);                             // chunk 2cc+1
        __syncthreads();
        if (cc < 14) pB = ldc(2 * cc + 4);
    }

    // ---- epilogue: out = acc + eps*x0 (C-layout: col=lane&15, row=q*4+reg) ----
    #pragma unroll
    for (int tt = 0; tt < 4; ++tt) {
        const int o = n0 + tt * 16 + lr;
        #pragma unroll
        for (int rr = 0; rr < 4; ++rr) {
            const int orow = i0 + m0 + q * 4 + rr;
            const size_t idx = ((size_t)(b * N_) + orow) * C_ + o;
            out[idx] = acc[tt][rr] + EPS_ * x0[idx];
        }
    }
}

extern "C" void kernel_launch(void* const* d_in, const int* in_sizes, int n_in,
                              void* d_out, int out_size, void* d_ws, size_t ws_size,
                              hipStream_t stream) {
    const float* x   = (const float*)d_in[0];
    const float* x0  = (const float*)d_in[1];
    const int*   adj = (const int*)d_in[2];
    const float* W   = (const float*)d_in[3];
    const float* wl  = (const float*)d_in[4];
    const float* wr  = (const float*)d_in[5];
    float* out = (float*)d_out;

    unsigned short* ht = (unsigned short*)d_ws;                      // 4 MB
    float* al = (float*)((char*)d_ws + (size_t)B_ * C_ * N_ * 2);
    float* ar = al + B_ * N_;
    unsigned short* Wt = (unsigned short*)(ar + B_ * N_);            // 32 KB
    unsigned int*   pkb = (unsigned int*)(Wt + C_ * C_);             // 4.2 MB

    k_pack<<<(B_ * N_ * N_) / 2048, 256, 0, stream>>>(adj, pkb);
    k_wt  <<<C_,             C_,  0, stream>>>(W, Wt);
    k_h   <<<B_ * (N_ / 64), 256, 0, stream>>>(x, Wt, wl, wr, ht, al, ar);
    k_out <<<B_ * (N_ / 32), 256, 0, stream>>>(pkb, ht, al, ar, x0, out);
}